// Round 11
// baseline (33.990 us; speedup 1.0000x reference)
//
#include <hip/hip_runtime.h>

#define BATCH 128
#define TLEN  160000
#define NSEG  200
#define CHUNK 8192
#define NCHUNK ((TLEN + CHUNK - 1) / CHUNK)   // 20
#define WPC   (CHUNK / 32)                    // 256 mask words per chunk
#define ITERS (CHUNK / 1024)                  // 8 float4s per thread

typedef float floatx4 __attribute__((ext_vector_type(4)));

// Single fused kernel. One block per (row, 8192-sample chunk).
//  (a) wave64 shuffle inclusive scan of the row's 200 segment lengths
//  (b) per-thread eff/start/end (exact reference float math)
//  (c) intersect each segment with this block's window; atomicOr-paint the
//      overlap into a 256-word LDS bitmask
//  (d) masked copy: fully-covered float4s skip the audio fetch;
//      output uses NONTEMPORAL stores (bypass L2/L3 allocation) so the
//      read stream keeps the caches.
__global__ void pl_fused(const float* __restrict__ audio,
                         const float* __restrict__ ratio,
                         const int* __restrict__ seg_len_raw,
                         const float* __restrict__ start_u,
                         float* __restrict__ out) {
    const int b    = blockIdx.y;
    const int tid  = threadIdx.x;
    const int wave = tid >> 6;
    const int lane = tid & 63;
    const int c0   = blockIdx.x * CHUNK;
    const int c1   = (c0 + CHUNK < TLEN) ? c0 + CHUNK : TLEN;

    __shared__ unsigned int lm[WPC];
    __shared__ int wsum[4];

    lm[tid] = 0u;                              // one word per thread

    const int base = b * NSEG;
    const int len  = (tid < NSEG) ? seg_len_raw[base + tid] : 0;

    // in-register inclusive scan within each wave (64 lanes)
    int incl = len;
    #pragma unroll
    for (int off = 1; off < 64; off <<= 1) {
        int t = __shfl_up(incl, off, 64);
        if (lane >= off) incl += t;
    }
    if (lane == 63) wsum[wave] = incl;
    __syncthreads();

    // add totals of preceding waves -> full inclusive scan over 256
    int woff = 0;
    #pragma unroll
    for (int w = 0; w < 4; ++w)
        if (w < wave) woff += wsum[w];
    incl += woff;

    // per-segment interval, clipped to this window, painted into LDS
    if (tid < NSEG) {
        int total = (int)floorf((float)TLEN * ratio[b]);    // matches reference
        int prev  = incl - len;                             // exclusive prefix
        int rem   = total - prev;
        int eff   = rem < 0 ? 0 : (rem > len ? len : rem);  // clip(total-prev,0,len)
        float u   = start_u[base + tid];
        int s0    = (int)floorf(u * (float)(TLEN - eff + 1));
        int s1    = s0 + eff;
        int a = (s0 > c0) ? s0 : c0;
        int e = (s1 < c1) ? s1 : c1;
        if (a < e) {
            int w0 = (a - c0) >> 5;
            int w1 = (e - 1 - c0) >> 5;                     // inclusive
            for (int w = w0; w <= w1; ++w) {
                int lo = (a - c0) - (w << 5); if (lo < 0) lo = 0;
                int hi = (e - c0) - (w << 5); if (hi > 32) hi = 32;
                unsigned int bits = (hi == 32 ? 0xFFFFFFFFu : ((1u << hi) - 1u))
                                  & ~((1u << lo) - 1u);
                atomicOr(&lm[w], bits);
            }
        }
    }
    __syncthreads();

    // masked copy: 8 float4s per thread
    const size_t rowbase = (size_t)b * TLEN;
    if (c0 + CHUNK <= TLEN) {
        // full block: branch-free unrolled loop
        #pragma unroll
        for (int i = 0; i < ITERS; ++i) {
            const int e4 = i * 256 + tid;
            const int s  = c0 + e4 * 4;
            unsigned int m4 = (lm[e4 >> 3] >> ((e4 & 7) * 4)) & 0xFu;
            const size_t idx = rowbase + s;
            floatx4 v;
            if (m4 == 0xFu) {
                v = (floatx4){0.f, 0.f, 0.f, 0.f};     // fully covered: skip fetch
            } else {
                v = __builtin_nontemporal_load((const floatx4*)(audio + idx));
                if (m4 & 1u) v.x = 0.f;
                if (m4 & 2u) v.y = 0.f;
                if (m4 & 4u) v.z = 0.f;
                if (m4 & 8u) v.w = 0.f;
            }
            __builtin_nontemporal_store(v, (floatx4*)(out + idx));
        }
    } else {
        // tail block: guarded loop
        for (int i = 0; i < ITERS; ++i) {
            const int e4 = i * 256 + tid;
            const int s  = c0 + e4 * 4;
            if (s >= TLEN) break;
            unsigned int m4 = (lm[e4 >> 3] >> ((e4 & 7) * 4)) & 0xFu;
            const size_t idx = rowbase + s;
            floatx4 v;
            if (m4 == 0xFu) {
                v = (floatx4){0.f, 0.f, 0.f, 0.f};
            } else {
                v = __builtin_nontemporal_load((const floatx4*)(audio + idx));
                if (m4 & 1u) v.x = 0.f;
                if (m4 & 2u) v.y = 0.f;
                if (m4 & 4u) v.z = 0.f;
                if (m4 & 8u) v.w = 0.f;
            }
            __builtin_nontemporal_store(v, (floatx4*)(out + idx));
        }
    }
}

extern "C" void kernel_launch(void* const* d_in, const int* in_sizes, int n_in,
                              void* d_out, int out_size, void* d_ws, size_t ws_size,
                              hipStream_t stream) {
    const float* audio       = (const float*)d_in[0];
    const float* ratio       = (const float*)d_in[1];
    const int*   seg_len_raw = (const int*)d_in[2];
    const float* start_u     = (const float*)d_in[3];
    float* out = (float*)d_out;

    dim3 grid(NCHUNK, BATCH);
    pl_fused<<<grid, 256, 0, stream>>>(audio, ratio, seg_len_raw, start_u, out);
}

// Round 12
// 27.114 us; speedup vs baseline: 1.2536x; 1.2536x over previous
//
#include <hip/hip_runtime.h>

#define BATCH 128
#define TLEN  160000
#define NSEG  200
#define CHUNK 8192
#define NCHUNK ((TLEN + CHUNK - 1) / CHUNK)   // 20
#define WPC   (CHUNK / 32)                    // 256 mask words per chunk
#define ITERS (CHUNK / 1024)                  // 8 float4s per thread

typedef float floatx4 __attribute__((ext_vector_type(4)));

// Single fused kernel. One block per (row, 8192-sample chunk).
//  (a) wave64 shuffle inclusive scan of the row's 200 segment lengths
//  (b) per-thread eff/start/end (exact reference float math)
//  (c) intersect each segment with this block's window; atomicOr-paint the
//      overlap into a 256-word LDS bitmask
//  (d) masked copy: fully-covered float4s skip the audio fetch.
//      Stores are NONTEMPORAL (out is never re-read; don't pollute L3);
//      loads are normal/cached (audio IS L3-resident across replays).
__global__ void pl_fused(const float* __restrict__ audio,
                         const float* __restrict__ ratio,
                         const int* __restrict__ seg_len_raw,
                         const float* __restrict__ start_u,
                         float* __restrict__ out) {
    const int b    = blockIdx.y;
    const int tid  = threadIdx.x;
    const int wave = tid >> 6;
    const int lane = tid & 63;
    const int c0   = blockIdx.x * CHUNK;
    const int c1   = (c0 + CHUNK < TLEN) ? c0 + CHUNK : TLEN;

    __shared__ unsigned int lm[WPC];
    __shared__ int wsum[4];

    lm[tid] = 0u;                              // one word per thread

    const int base = b * NSEG;
    const int len  = (tid < NSEG) ? seg_len_raw[base + tid] : 0;

    // in-register inclusive scan within each wave (64 lanes)
    int incl = len;
    #pragma unroll
    for (int off = 1; off < 64; off <<= 1) {
        int t = __shfl_up(incl, off, 64);
        if (lane >= off) incl += t;
    }
    if (lane == 63) wsum[wave] = incl;
    __syncthreads();

    // add totals of preceding waves -> full inclusive scan over 256
    int woff = 0;
    #pragma unroll
    for (int w = 0; w < 4; ++w)
        if (w < wave) woff += wsum[w];
    incl += woff;

    // per-segment interval, clipped to this window, painted into LDS
    if (tid < NSEG) {
        int total = (int)floorf((float)TLEN * ratio[b]);    // matches reference
        int prev  = incl - len;                             // exclusive prefix
        int rem   = total - prev;
        int eff   = rem < 0 ? 0 : (rem > len ? len : rem);  // clip(total-prev,0,len)
        float u   = start_u[base + tid];
        int s0    = (int)floorf(u * (float)(TLEN - eff + 1));
        int s1    = s0 + eff;
        int a = (s0 > c0) ? s0 : c0;
        int e = (s1 < c1) ? s1 : c1;
        if (a < e) {
            int w0 = (a - c0) >> 5;
            int w1 = (e - 1 - c0) >> 5;                     // inclusive
            for (int w = w0; w <= w1; ++w) {
                int lo = (a - c0) - (w << 5); if (lo < 0) lo = 0;
                int hi = (e - c0) - (w << 5); if (hi > 32) hi = 32;
                unsigned int bits = (hi == 32 ? 0xFFFFFFFFu : ((1u << hi) - 1u))
                                  & ~((1u << lo) - 1u);
                atomicOr(&lm[w], bits);
            }
        }
    }
    __syncthreads();

    // masked copy: 8 float4s per thread
    const size_t rowbase = (size_t)b * TLEN;
    if (c0 + CHUNK <= TLEN) {
        // full block: branch-free unrolled loop
        #pragma unroll
        for (int i = 0; i < ITERS; ++i) {
            const int e4 = i * 256 + tid;
            const int s  = c0 + e4 * 4;
            unsigned int m4 = (lm[e4 >> 3] >> ((e4 & 7) * 4)) & 0xFu;
            const size_t idx = rowbase + s;
            floatx4 v;
            if (m4 == 0xFu) {
                v = (floatx4){0.f, 0.f, 0.f, 0.f};     // fully covered: skip fetch
            } else {
                v = *(const floatx4*)(audio + idx);    // cached load
                if (m4 & 1u) v.x = 0.f;
                if (m4 & 2u) v.y = 0.f;
                if (m4 & 4u) v.z = 0.f;
                if (m4 & 8u) v.w = 0.f;
            }
            __builtin_nontemporal_store(v, (floatx4*)(out + idx));
        }
    } else {
        // tail block: guarded loop
        for (int i = 0; i < ITERS; ++i) {
            const int e4 = i * 256 + tid;
            const int s  = c0 + e4 * 4;
            if (s >= TLEN) break;
            unsigned int m4 = (lm[e4 >> 3] >> ((e4 & 7) * 4)) & 0xFu;
            const size_t idx = rowbase + s;
            floatx4 v;
            if (m4 == 0xFu) {
                v = (floatx4){0.f, 0.f, 0.f, 0.f};
            } else {
                v = *(const floatx4*)(audio + idx);
                if (m4 & 1u) v.x = 0.f;
                if (m4 & 2u) v.y = 0.f;
                if (m4 & 4u) v.z = 0.f;
                if (m4 & 8u) v.w = 0.f;
            }
            __builtin_nontemporal_store(v, (floatx4*)(out + idx));
        }
    }
}

extern "C" void kernel_launch(void* const* d_in, const int* in_sizes, int n_in,
                              void* d_out, int out_size, void* d_ws, size_t ws_size,
                              hipStream_t stream) {
    const float* audio       = (const float*)d_in[0];
    const float* ratio       = (const float*)d_in[1];
    const int*   seg_len_raw = (const int*)d_in[2];
    const float* start_u     = (const float*)d_in[3];
    float* out = (float*)d_out;

    dim3 grid(NCHUNK, BATCH);
    pl_fused<<<grid, 256, 0, stream>>>(audio, ratio, seg_len_raw, start_u, out);
}